// Round 3
// baseline (576.967 us; speedup 1.0000x reference)
//
#include <hip/hip_runtime.h>
#include <hip/hip_fp16.h>

typedef unsigned short u16;
typedef __attribute__((ext_vector_type(4))) float f32x4;
typedef __attribute__((ext_vector_type(8))) _Float16 f16x8;
typedef __attribute__((ext_vector_type(8))) unsigned short u16x8;
typedef __attribute__((ext_vector_type(4))) unsigned short u16x4;

#define DEVI __device__ __forceinline__
#define MASKV (-1000.0f)

DEVI u16 f2h(float f){ __half h = __float2half(f); return __half_as_ushort(h); }
DEVI float h2f(u16 v){ return __half2float(__ushort_as_half(v)); }
DEVI float sigm(float s){ float e = __expf(-fabsf(s)); return (s >= 0.f) ? 1.f/(1.f+e) : e/(1.f+e); }

DEVI void async16(const void* g, void* l){
  __builtin_amdgcn_global_load_lds((__attribute__((address_space(1))) const unsigned int*)g,
                                   (__attribute__((address_space(3))) unsigned int*)l, 16, 0, 0);
}

struct Acc { f32x4 a[4][4]; };
DEVI void acc_zero(Acc& a){
  f32x4 z = {0.f,0.f,0.f,0.f};
  #pragma unroll
  for (int i=0;i<4;i++)
    #pragma unroll
    for (int j=0;j<4;j++) a.a[i][j] = z;
}

// C[M x N] = A[M x K] * Bt[N x K]^T   (fp16, 128x128 tile, BK=32, m97 structure)
DEVI void gemm_core(const u16* __restrict__ A, int lda, const u16* __restrict__ Bt, int ldb,
                    int K, u16* As, u16* Bs, Acc& acc, int tid)
{
  int w = tid >> 6, l = tid & 63;
  int q = l >> 4, m = l & 15;
  int wm = w & 1, wn = w >> 1;
  for (int k0 = 0; k0 < K; k0 += 32){
    __syncthreads();
    #pragma unroll
    for (int p = 0; p < 2; p++){
      int row = w*32 + p*16 + (l>>2);
      async16(A  + (size_t)row*lda + k0 + (l&3)*8, As + (w*32 + p*16)*32);
      async16(Bt + (size_t)row*ldb + k0 + (l&3)*8, Bs + (w*32 + p*16)*32);
    }
    __syncthreads();
    f16x8 af[4], bf[4];
    #pragma unroll
    for (int t = 0; t < 4; t++){
      af[t] = *(const f16x8*)(As + (wm*64 + t*16 + m)*32 + q*8);
      bf[t] = *(const f16x8*)(Bs + (wn*64 + t*16 + m)*32 + q*8);
    }
    #pragma unroll
    for (int i = 0; i < 4; i++)
      #pragma unroll
      for (int j = 0; j < 4; j++)
        acc.a[i][j] = __builtin_amdgcn_mfma_f32_16x16x32_f16(af[i], bf[j], acc.a[i][j], 0, 0, 0);
  }
}

// ---------------- elementwise convert f32 -> fp16 ----------------
__global__ __launch_bounds__(256) void k_cvt(const float* __restrict__ src, u16* __restrict__ dst, int n){
  int i = (blockIdx.x*256 + threadIdx.x)*4;
  if (i < n){
    f32x4 v = *(const f32x4*)(src + i);
    u16x4 o;
    #pragma unroll
    for (int z=0; z<4; z++) o[z] = f2h(v[z]);
    *(u16x4*)(dst + i) = o;
  }
}

// ---------------- transpose f32 [R][C] -> fp16 [C][R] ----------------
__global__ __launch_bounds__(256) void k_transpose_f(const float* __restrict__ src, u16* __restrict__ dst,
    int R, int C){
  __shared__ u16 t[32][33];
  int c0 = blockIdx.x*32, r0 = blockIdx.y*32;
  int tx = threadIdx.x & 31, ty = threadIdx.x >> 5;
  #pragma unroll
  for (int i = ty; i < 32; i += 8){
    int r = r0 + i, c = c0 + tx;
    if (r < R && c < C) t[i][tx] = f2h(src[(size_t)r*C + c]);
  }
  __syncthreads();
  #pragma unroll
  for (int i = ty; i < 32; i += 8){
    int rr = c0 + i, cc = r0 + tx;
    if (rr < C && cc < R) dst[(size_t)rr*R + cc] = t[tx][i];
  }
}

// ---------------- transpose u16 [R][C] -> [C][R], batched ----------------
__global__ __launch_bounds__(256) void k_transpose_h(const u16* __restrict__ src, u16* __restrict__ dst,
    int R, int C, long sps, long dps){
  __shared__ u16 t[32][33];
  src += (size_t)blockIdx.z * sps; dst += (size_t)blockIdx.z * dps;
  int c0 = blockIdx.x*32, r0 = blockIdx.y*32;
  int tx = threadIdx.x & 31, ty = threadIdx.x >> 5;
  #pragma unroll
  for (int i = ty; i < 32; i += 8){
    int r = r0 + i, c = c0 + tx;
    if (r < R && c < C) t[i][tx] = src[(size_t)r*C + c];
  }
  __syncthreads();
  #pragma unroll
  for (int i = ty; i < 32; i += 8){
    int rr = c0 + i, cc = r0 + tx;
    if (rr < C && cc < R) dst[(size_t)rr*R + cc] = t[tx][i];
  }
}

// ---------------- QKV + vgate projections ----------------
struct ProjArgs {
  const u16* xh;
  const u16* wT0; const u16* wT1; const u16* wT2; const u16* wT3;
  u16* q; u16* k; u16* v; u16* vg;
  const float* bvg;
};
__global__ __launch_bounds__(256) void k_proj(ProjArgs p){
  __shared__ __align__(16) u16 As[4096];
  __shared__ __align__(16) u16 Bs[4096];
  int z = blockIdx.z;
  const u16* wT = (z==0) ? p.wT0 : (z==1) ? p.wT1 : (z==2) ? p.wT2 : p.wT3;
  int tid = threadIdx.x;
  Acc acc; acc_zero(acc);
  const u16* A  = p.xh + (size_t)blockIdx.x*128*2048;
  const u16* Bt = wT   + (size_t)blockIdx.y*128*2048;
  gemm_core(A, 2048, Bt, 2048, 2048, As, Bs, acc, tid);
  int w = tid>>6, l = tid&63, q4 = l>>4, m = l&15, wm = w&1, wn = w>>1;
  #pragma unroll
  for (int ti=0; ti<4; ti++)
  #pragma unroll
  for (int tj=0; tj<4; tj++)
  #pragma unroll
  for (int r=0; r<4; r++){
    int trow = blockIdx.x*128 + wm*64 + ti*16 + q4*4 + r;
    int col  = blockIdx.y*128 + wn*64 + tj*16 + m;
    float v = acc.a[ti][tj][r];
    if (z == 3){
      float sg = sigm(v + p.bvg[col]);
      p.vg[(size_t)trow*2048 + col] = f2h(sg);
    } else {
      int b = trow >> 10, i = trow & 1023, h = col >> 7, d = col & 127;
      u16* dst = (z==0) ? p.q : (z==1) ? p.k : p.v;
      dst[(((size_t)(b*16 + h))*1024 + i)*128 + d] = f2h(v);
    }
  }
}

// ---------------- head gate: sigmoid(x @ w_hgate + b) ----------------
__global__ __launch_bounds__(256) void k_hgate(const u16* __restrict__ xh, const u16* __restrict__ whgT,
    const float* __restrict__ bhg, float* __restrict__ hg){
  int tid = threadIdx.x, w = tid>>6, l = tid&63, q = l>>4, m = l&15;
  int t0 = blockIdx.x*64 + w*16;
  f32x4 acc = {0.f,0.f,0.f,0.f};
  const u16* xr = xh   + (size_t)(t0 + m)*2048;
  const u16* br = whgT + (size_t)m*2048;
  for (int k = 0; k < 2048; k += 32){
    f16x8 a = *(const f16x8*)(xr + k + q*8);
    f16x8 b = *(const f16x8*)(br + k + q*8);
    acc = __builtin_amdgcn_mfma_f32_16x16x32_f16(a, b, acc, 0, 0, 0);
  }
  float bias = bhg[m];
  #pragma unroll
  for (int r = 0; r < 4; r++){
    int tok = t0 + q*4 + r;
    hg[(size_t)tok*16 + m] = sigm(acc[r] + bias);
  }
}

// ---------------- q,k l2norm + rotary (in place) + CoPE logits L ----------------
__global__ __launch_bounds__(256) void k_normrope(u16* __restrict__ qb, u16* __restrict__ kb,
    const float* __restrict__ freqs, const float* __restrict__ cope, float* __restrict__ L){
  __shared__ float ce[2048];
  int tid = threadIdx.x;
  for (int i2 = tid; i2 < 2048; i2 += 256) ce[i2] = cope[i2];
  __syncthreads();
  int w = tid >> 6, l = tid & 63;
  int r = blockIdx.x*4 + w;            // 0..65535
  int isq = (r < 32768) ? 1 : 0;
  int rr = isq ? r : r - 32768;
  int i = rr & 1023;
  u16* base = (isq ? qb : kb) + (size_t)rr*128;
  float v0 = h2f(base[2*l]), v1 = h2f(base[2*l+1]);
  float ss = v0*v0 + v1*v1;
  #pragma unroll
  for (int off = 1; off < 64; off <<= 1) ss += __shfl_xor(ss, off);
  float rn = 1.f / fmaxf(sqrtf(ss), 1e-12f);
  v0 *= rn; v1 *= rn;
  float f = freqs[i*128 + 2*l];
  float sn, cs; sincosf(f, &sn, &cs);
  float o0 = v0*cs - v1*sn, o1 = v1*cs + v0*sn;
  base[2*l] = f2h(o0); base[2*l+1] = f2h(o1);
  if (isq){
    #pragma unroll
    for (int p = 0; p < 16; p++){
      float part = o0*ce[p*128 + 2*l] + o1*ce[p*128 + 2*l + 1];
      #pragma unroll
      for (int off = 1; off < 64; off <<= 1) part += __shfl_xor(part, off);
      if (l == p) L[(size_t)rr*16 + p] = part;
    }
  }
}

// ---------------- sim = 10 * q k^T, causal-packed fp16 (mask = MASKV) ----------------
__global__ __launch_bounds__(256) void k_qk(const u16* __restrict__ qb, const u16* __restrict__ kb,
    u16* __restrict__ S){
  __shared__ __align__(16) u16 As[4096];
  __shared__ __align__(16) u16 Bs[4096];
  int tile = blockIdx.x, bh = blockIdx.y;
  int it = 0;
  #pragma unroll
  for (int t2 = 1; t2 < 8; t2++) if (tile >= (t2*(t2+1))/2) it = t2;
  int jt = tile - (it*(it+1))/2;
  const u16* A  = qb + (size_t)bh*131072 + (size_t)it*16384;
  const u16* Bt = kb + (size_t)bh*131072 + (size_t)jt*16384;
  Acc acc; acc_zero(acc);
  gemm_core(A, 128, Bt, 128, 128, As, Bs, acc, threadIdx.x);
  int tid = threadIdx.x, w = tid>>6, l = tid&63, q = l>>4, m = l&15, wm = w&1, wn = w>>1;
  u16* dst = S + ((size_t)bh*36 + tile)*16384;
  #pragma unroll
  for (int ti=0; ti<4; ti++)
  #pragma unroll
  for (int tj=0; tj<4; tj++)
  #pragma unroll
  for (int r=0; r<4; r++){
    int iloc = wm*64 + ti*16 + q*4 + r;
    int jloc = wn*64 + tj*16 + m;
    float v = acc.a[ti][tj][r] * 10.f;
    if (jt*128 + jloc > it*128 + iloc) v = MASKV;
    dst[(size_t)iloc*128 + jloc] = f2h(v);
  }
}

// ---------------- th_pre mix (VALU) + CoPE + online softmax stats (in-place S) ----------------
struct CopeArgs { const u16* S; const float* L; const float* thpre; u16* Sout; float* ml; };
__global__ __launch_bounds__(1024) void k_cope(CopeArgs pa){
  __shared__ u16 raw[16*260];       // [g][ii*64+j], stride 260
  __shared__ float thsh[256];       // th_pre[h][g]
  __shared__ float Lsh[1024];       // [h][ii][p]
  int b = blockIdx.y;
  int i0 = (int)(gridDim.x - 1 - blockIdx.x) * 4;   // heavy blocks first
  int tid = threadIdx.x, w = tid>>6, l = tid&63;
  int h = w;                                         // 16 waves = 16 heads
  if (tid < 256) thsh[tid] = pa.thpre[tid];
  Lsh[tid] = pa.L[ ((size_t)((b*16 + (tid>>6))*1024) + i0 + ((tid>>4)&3))*16 + (tid&15) ];
  __syncthreads();
  float th_r[16];
  #pragma unroll
  for (int g = 0; g < 16; g++) th_r[g] = thsh[h*16 + g];
  float carry[4] = {0.f,0.f,0.f,0.f};
  float mrun[4]  = {-1e30f,-1e30f,-1e30f,-1e30f};
  float lrun[4]  = {0.f,0.f,0.f,0.f};
  int tmax = (i0 + 3) >> 6;
  for (int t = tmax; t >= 0; t--){
    __syncthreads();
    {
      int e = tid*4;                 // [0,4096)
      int g = e >> 8, r = e & 255;
      int ii = r >> 6, j = r & 63;
      int i = i0 + ii; int it1 = i >> 7, iloc = i & 127;
      int jt1 = (t*64) >> 7, jo = (t*64) & 127;
      const u16* src = pa.S + ((size_t)((b*16+g)*36 + (it1*(it1+1))/2 + jt1))*16384
                           + (size_t)iloc*128 + jo + j;
      *(u16x4*)(raw + g*260 + r) = *(const u16x4*)src;
    }
    __syncthreads();
    #pragma unroll
    for (int ii = 0; ii < 4; ii++){
      float s = 0.f;
      #pragma unroll
      for (int g = 0; g < 16; g++) s += th_r[g] * h2f(raw[g*260 + ii*64 + l]);
      float gg = sigm(s);
      float suf = gg;
      #pragma unroll
      for (int off = 1; off < 64; off <<= 1){
        int srcl = l + off;
        float tv = __shfl(suf, srcl & 63);
        suf += (srcl < 64) ? tv : 0.f;
      }
      float pos = fminf(suf + carry[ii], 15.f);
      pos = fmaxf(pos, 0.f);
      float pf = floorf(pos);
      float wi = pos - pf;
      int ic = (int)ceilf(pos), ifl = (int)pf;
      float sf = s + Lsh[h*64 + ii*16 + ic]*wi + Lsh[h*64 + ii*16 + ifl]*(1.f - wi);
      sf = h2f(f2h(sf));             // round now; stats use the stored value
      {
        int i = i0 + ii; int it1 = i>>7, iloc = i&127;
        int jt1 = (t*64)>>7, jo = (t*64)&127;
        pa.Sout[((size_t)((b*16+h)*36 + (it1*(it1+1))/2 + jt1))*16384 + (size_t)iloc*128 + jo + l] = f2h(sf);
      }
      float tmx = sf;
      #pragma unroll
      for (int off = 1; off < 64; off <<= 1) tmx = fmaxf(tmx, __shfl_xor(tmx, off));
      float mnew = fmaxf(mrun[ii], tmx);
      float ex = __expf(fminf(sf - mnew, 0.f));
      float sm = ex;
      #pragma unroll
      for (int off = 1; off < 64; off <<= 1) sm += __shfl_xor(sm, off);
      lrun[ii] = lrun[ii]*__expf(fminf(mrun[ii] - mnew, 0.f)) + sm;
      mrun[ii] = mnew;
      carry[ii] += __shfl(suf, 0);
    }
  }
  if (l == 0){
    size_t bix = (size_t)(b*16 + h)*1024 + i0;
    #pragma unroll
    for (int ii=0; ii<4; ii++){
      pa.ml[bix+ii] = mrun[ii];
      pa.ml[32768 + bix + ii] = 1.f/fmaxf(lrun[ii], 1e-30f);
    }
  }
}

// ---------------- softmax normalize + th_post mix (VALU, in-place S -> attn2) ----------------
struct PostArgs { const u16* S; const float* ml; const float* thpost; u16* Sout; };
__global__ __launch_bounds__(256) void k_postmix(PostArgs pa){
  __shared__ u16 at[16*1040];        // [g][e], stride 1040
  __shared__ float thsh[256];
  __shared__ float mh[128], rlh[128];
  int tile = blockIdx.x >> 4, sub = blockIdx.x & 15, b = blockIdx.y;
  int it = 0;
  #pragma unroll
  for (int t2=1; t2<8; t2++) if (tile >= (t2*(t2+1))/2) it = t2;
  int tid = threadIdx.x;
  thsh[tid] = pa.thpost[tid];
  if (tid < 128){
    int g = tid >> 3, ii = tid & 7;
    size_t ix = (size_t)(b*16+g)*1024 + it*128 + sub*8 + ii;
    mh[tid] = pa.ml[ix]; rlh[tid] = pa.ml[32768 + ix];
  }
  __syncthreads();
  {
    int g = tid >> 4, l16 = tid & 15;
    const u16* src = pa.S + ((size_t)((b*16+g)*36 + tile))*16384 + sub*1024;
    #pragma unroll
    for (int c = 0; c < 16; c++){
      int e = c*64 + l16*4;
      int ii = e >> 7;
      float mm = mh[g*8+ii], rr = rlh[g*8+ii];
      u16x4 sv = *(const u16x4*)(src + e);
      u16x4 o;
      #pragma unroll
      for (int z2=0; z2<4; z2++) o[z2] = f2h(__expf(fminf(h2f(sv[z2]) - mm, 0.f)) * rr);
      *(u16x4*)(at + g*1040 + e) = o;
    }
  }
  __syncthreads();
  int h = tid >> 4, c16 = tid & 15;
  float th_r[16];
  #pragma unroll
  for (int g = 0; g < 16; g++) th_r[g] = thsh[h*16 + g];
  u16* dst = pa.Sout + ((size_t)((b*16+h)*36 + tile))*16384 + sub*1024;
  #pragma unroll
  for (int k = 0; k < 16; k++){
    int e = c16*4 + k*64;
    float a0=0.f, a1=0.f, a2=0.f, a3=0.f;
    #pragma unroll
    for (int g = 0; g < 16; g++){
      u16x4 v4 = *(const u16x4*)(at + g*1040 + e);
      float tg = th_r[g];
      a0 += tg*h2f(v4[0]); a1 += tg*h2f(v4[1]); a2 += tg*h2f(v4[2]); a3 += tg*h2f(v4[3]);
    }
    u16x4 o; o[0]=f2h(a0); o[1]=f2h(a1); o[2]=f2h(a2); o[3]=f2h(a3);
    *(u16x4*)(dst + e) = o;
  }
}

// ---------------- out = attn2 @ v, fused head/value gates ----------------
struct PvArgs { const u16* S; const u16* vT; const float* hg; const u16* vg; u16* gated; };
__global__ __launch_bounds__(256) void k_pv(PvArgs pa){
  __shared__ __align__(16) u16 As[2048];
  __shared__ __align__(16) u16 Bs[4096];
  int bh = blockIdx.y, b = bh >> 4, h = bh & 15;
  int isub = (int)(gridDim.x - 1 - blockIdx.x);   // heavy blocks first
  int i0 = isub * 64;
  int it1 = i0 >> 7, ibase = i0 & 127;
  int nk = (i0 + 64) / 32;
  const u16* abase = pa.S  + ((size_t)(bh*36 + (it1*(it1+1))/2))*16384;
  const u16* vt    = pa.vT + (size_t)bh*131072;
  int tid = threadIdx.x, w = tid>>6, l = tid&63, q = l>>4, m = l&15, wm = w&1, wn = w>>1;
  f32x4 acc[2][4];
  { f32x4 z = {0.f,0.f,0.f,0.f};
    #pragma unroll
    for (int i2=0;i2<2;i2++)
      #pragma unroll
      for (int j2=0;j2<4;j2++) acc[i2][j2] = z; }
  for (int ks = 0; ks < nk; ks++){
    __syncthreads();
    {
      int row = w*16 + (l>>2);
      async16(abase + (size_t)(ks>>2)*16384 + (size_t)(ibase + row)*128 + (ks&3)*32 + (l&3)*8,
              As + (w*16)*32);
    }
    #pragma unroll
    for (int p2=0; p2<2; p2++){
      int row = w*32 + p2*16 + (l>>2);
      async16(vt + (size_t)row*1024 + ks*32 + (l&3)*8, Bs + (w*32 + p2*16)*32);
    }
    __syncthreads();
    f16x8 af[2], bf[4];
    #pragma unroll
    for (int t=0;t<2;t++) af[t] = *(const f16x8*)(As + (wm*32 + t*16 + m)*32 + q*8);
    #pragma unroll
    for (int t=0;t<4;t++) bf[t] = *(const f16x8*)(Bs + (wn*64 + t*16 + m)*32 + q*8);
    #pragma unroll
    for (int i2=0;i2<2;i2++)
      #pragma unroll
      for (int j2=0;j2<4;j2++)
        acc[i2][j2] = __builtin_amdgcn_mfma_f32_16x16x32_f16(af[i2], bf[j2], acc[i2][j2], 0, 0, 0);
  }
  #pragma unroll
  for (int ti=0; ti<2; ti++)
  #pragma unroll
  for (int tj=0; tj<4; tj++)
  #pragma unroll
  for (int r=0; r<4; r++){
    int i = i0 + wm*32 + ti*16 + q*4 + r;
    int d = wn*64 + tj*16 + m;
    int tok = b*1024 + i;
    float v = acc[ti][tj][r] * pa.hg[(size_t)tok*16 + h] * h2f(pa.vg[(size_t)tok*2048 + h*128 + d]);
    if (v != v) v = 333.f;           // NaN tag: PV-level
    pa.gated[(size_t)tok*2048 + h*128 + d] = f2h(v);
  }
}

// ---------------- final projection -> f32 d_out ----------------
__global__ __launch_bounds__(256) void k_out(const u16* __restrict__ gated, const u16* __restrict__ woT,
    float* __restrict__ out){
  __shared__ __align__(16) u16 As[4096];
  __shared__ __align__(16) u16 Bs[4096];
  Acc acc; acc_zero(acc);
  gemm_core(gated + (size_t)blockIdx.x*128*2048, 2048,
            woT   + (size_t)blockIdx.y*128*2048, 2048, 2048, As, Bs, acc, threadIdx.x);
  int tid = threadIdx.x, w = tid>>6, l = tid&63, q = l>>4, m = l&15, wm = w&1, wn = w>>1;
  #pragma unroll
  for (int ti=0; ti<4; ti++)
  #pragma unroll
  for (int tj=0; tj<4; tj++)
  #pragma unroll
  for (int r=0; r<4; r++){
    int trow = blockIdx.x*128 + wm*64 + ti*16 + q*4 + r;
    int col  = blockIdx.y*128 + wn*64 + tj*16 + m;
    float o = acc.a[ti][tj][r];
    if (o != o) o = 911.f;           // NaN tag: output-GEMM level
    out[(size_t)trow*2048 + col] = o;
  }
}

extern "C" void kernel_launch(void* const* d_in, const int* in_sizes, int n_in,
                              void* d_out, int out_size, void* d_ws, size_t ws_size,
                              hipStream_t stream){
  const float* x      = (const float*)d_in[0];
  const float* freqs  = (const float*)d_in[1];
  const float* w_q    = (const float*)d_in[2];
  const float* w_k    = (const float*)d_in[3];
  const float* w_v    = (const float*)d_in[4];
  const float* cope   = (const float*)d_in[5];
  const float* thpre  = (const float*)d_in[6];
  const float* thpost = (const float*)d_in[7];
  const float* w_vg   = (const float*)d_in[8];
  const float* b_vg   = (const float*)d_in[9];
  const float* w_hg   = (const float*)d_in[10];
  const float* b_hg   = (const float*)d_in[11];
  const float* w_out  = (const float*)d_in[12];

  char* ws = (char*)d_ws;
  size_t off = 0;
  auto alloc = [&](size_t bytes)->char*{ char* r = ws + off; off += (bytes + 255) & ~(size_t)255; return r; };
  u16*   xh    = (u16*)  alloc(8388608);
  u16*   wqT   = (u16*)  alloc(8388608);
  u16*   wkT   = (u16*)  alloc(8388608);
  u16*   wvT   = (u16*)  alloc(8388608);
  u16*   wvgT  = (u16*)  alloc(8388608);
  u16*   woT   = (u16*)  alloc(8388608);
  u16*   whgT  = (u16*)  alloc(65536);
  u16*   qb    = (u16*)  alloc(8388608);
  u16*   kb    = (u16*)  alloc(8388608);
  u16*   vb    = (u16*)  alloc(8388608);
  u16*   vTT   = (u16*)  alloc(8388608);
  u16*   vg    = (u16*)  alloc(8388608);
  u16*   gated = (u16*)  alloc(8388608);
  float* L     = (float*)alloc(2097152);
  float* hg    = (float*)alloc(131072);
  float* ml    = (float*)alloc(262144);
  u16*   S     = (u16*)  alloc(37748736);

  dim3 b256(256);
  k_cvt<<<dim3(4096), b256, 0, stream>>>(x, xh, 4194304);
  k_transpose_f<<<dim3(64,64), b256, 0, stream>>>(w_q,  wqT,  2048, 2048);
  k_transpose_f<<<dim3(64,64), b256, 0, stream>>>(w_k,  wkT,  2048, 2048);
  k_transpose_f<<<dim3(64,64), b256, 0, stream>>>(w_v,  wvT,  2048, 2048);
  k_transpose_f<<<dim3(64,64), b256, 0, stream>>>(w_vg, wvgT, 2048, 2048);
  k_transpose_f<<<dim3(64,64), b256, 0, stream>>>(w_out, woT, 2048, 2048);
  k_transpose_f<<<dim3(1,64),  b256, 0, stream>>>(w_hg, whgT, 2048, 16);

  ProjArgs pa{ xh, wqT, wkT, wvT, wvgT, qb, kb, vb, vg, b_vg };
  k_proj<<<dim3(16,16,4), b256, 0, stream>>>(pa);
  k_hgate<<<dim3(32), b256, 0, stream>>>(xh, whgT, b_hg, hg);
  k_transpose_h<<<dim3(4,32,32), b256, 0, stream>>>(vb, vTT, 1024, 128, 131072L, 131072L);
  k_normrope<<<dim3(16384), b256, 0, stream>>>(qb, kb, freqs, cope, L);
  k_qk<<<dim3(36,32), b256, 0, stream>>>(qb, kb, S);
  CopeArgs ca{ S, L, thpre, S, ml };
  k_cope<<<dim3(256,2), dim3(1024), 0, stream>>>(ca);
  PostArgs po{ S, ml, thpost, S };
  k_postmix<<<dim3(576,2), b256, 0, stream>>>(po);
  PvArgs pv{ S, vTT, hg, vg, gated };
  k_pv<<<dim3(16,32), b256, 0, stream>>>(pv);
  k_out<<<dim3(16,16), b256, 0, stream>>>(gated, woT, (float*)d_out);
}

// Round 4
// 509.789 us; speedup vs baseline: 1.1318x; 1.1318x over previous
//
#include <hip/hip_runtime.h>
#include <hip/hip_fp16.h>

typedef unsigned short u16;
typedef __attribute__((ext_vector_type(4))) float f32x4;
typedef __attribute__((ext_vector_type(8))) _Float16 f16x8;
typedef __attribute__((ext_vector_type(4))) _Float16 f16x4;
typedef __attribute__((ext_vector_type(8))) unsigned short u16x8;
typedef __attribute__((ext_vector_type(4))) unsigned short u16x4;

#define DEVI __device__ __forceinline__
#define MASKV (-1000.0f)

DEVI u16 f2h(float f){ __half h = __float2half(f); return __half_as_ushort(h); }
DEVI float h2f(u16 v){ return __half2float(__ushort_as_half(v)); }
DEVI float sigm(float s){ float e = __expf(-fabsf(s)); return (s >= 0.f) ? 1.f/(1.f+e) : e/(1.f+e); }

DEVI void async16(const void* g, void* l){
  __builtin_amdgcn_global_load_lds((__attribute__((address_space(1))) const unsigned int*)g,
                                   (__attribute__((address_space(3))) unsigned int*)l, 16, 0, 0);
}

struct Acc { f32x4 a[4][4]; };
DEVI void acc_zero(Acc& a){
  f32x4 z = {0.f,0.f,0.f,0.f};
  #pragma unroll
  for (int i=0;i<4;i++)
    #pragma unroll
    for (int j=0;j<4;j++) a.a[i][j] = z;
}

// C[M x N] = A[M x K] * Bt[N x K]^T   (fp16, 128x128 tile, BK=32, m97 structure)
DEVI void gemm_core(const u16* __restrict__ A, int lda, const u16* __restrict__ Bt, int ldb,
                    int K, u16* As, u16* Bs, Acc& acc, int tid)
{
  int w = tid >> 6, l = tid & 63;
  int q = l >> 4, m = l & 15;
  int wm = w & 1, wn = w >> 1;
  for (int k0 = 0; k0 < K; k0 += 32){
    __syncthreads();
    #pragma unroll
    for (int p = 0; p < 2; p++){
      int row = w*32 + p*16 + (l>>2);
      async16(A  + (size_t)row*lda + k0 + (l&3)*8, As + (w*32 + p*16)*32);
      async16(Bt + (size_t)row*ldb + k0 + (l&3)*8, Bs + (w*32 + p*16)*32);
    }
    __syncthreads();
    f16x8 af[4], bf[4];
    #pragma unroll
    for (int t = 0; t < 4; t++){
      af[t] = *(const f16x8*)(As + (wm*64 + t*16 + m)*32 + q*8);
      bf[t] = *(const f16x8*)(Bs + (wn*64 + t*16 + m)*32 + q*8);
    }
    #pragma unroll
    for (int i = 0; i < 4; i++)
      #pragma unroll
      for (int j = 0; j < 4; j++)
        acc.a[i][j] = __builtin_amdgcn_mfma_f32_16x16x32_f16(af[i], bf[j], acc.a[i][j], 0, 0, 0);
  }
}

// ---------------- fused prep: x convert (z=0) + 6 weight transposes (z=1..6) ----------------
struct PrepArgs {
  const float* src[7];
  u16* dst[7];
  int C[7];
};
__global__ __launch_bounds__(256) void k_prep(PrepArgs p){
  __shared__ u16 t[32][33];
  int z = blockIdx.z;
  if (z == 0){
    int i = ((blockIdx.y*64 + blockIdx.x)*256 + threadIdx.x)*4;
    f32x4 v = *(const f32x4*)(p.src[0] + i);
    u16x4 o;
    #pragma unroll
    for (int z2=0; z2<4; z2++) o[z2] = f2h(v[z2]);
    *(u16x4*)(p.dst[0] + i) = o;
    return;
  }
  const float* src = p.src[z]; u16* dst = p.dst[z];
  int R = 2048, C = p.C[z];
  int c0 = blockIdx.x*32, r0 = blockIdx.y*32;
  if (c0 >= C) return;
  int tx = threadIdx.x & 31, ty = threadIdx.x >> 5;
  #pragma unroll
  for (int i = ty; i < 32; i += 8){
    int r = r0 + i, c = c0 + tx;
    if (r < R && c < C) t[i][tx] = f2h(src[(size_t)r*C + c]);
  }
  __syncthreads();
  #pragma unroll
  for (int i = ty; i < 32; i += 8){
    int rr = c0 + i, cc = r0 + tx;
    if (rr < C && cc < R) dst[(size_t)rr*R + cc] = t[tx][i];
  }
}

// ---------------- transpose u16 [R][C] -> [C][R], batched ----------------
__global__ __launch_bounds__(256) void k_transpose_h(const u16* __restrict__ src, u16* __restrict__ dst,
    int R, int C, long sps, long dps){
  __shared__ u16 t[32][33];
  src += (size_t)blockIdx.z * sps; dst += (size_t)blockIdx.z * dps;
  int c0 = blockIdx.x*32, r0 = blockIdx.y*32;
  int tx = threadIdx.x & 31, ty = threadIdx.x >> 5;
  #pragma unroll
  for (int i = ty; i < 32; i += 8){
    int r = r0 + i, c = c0 + tx;
    if (r < R && c < C) t[i][tx] = src[(size_t)r*C + c];
  }
  __syncthreads();
  #pragma unroll
  for (int i = ty; i < 32; i += 8){
    int rr = c0 + i, cc = r0 + tx;
    if (rr < C && cc < R) dst[(size_t)rr*R + cc] = t[tx][i];
  }
}

// ---------------- QKV + vgate projections ----------------
struct ProjArgs {
  const u16* xh;
  const u16* wT0; const u16* wT1; const u16* wT2; const u16* wT3;
  u16* q; u16* k; u16* v; u16* vg;
  const float* bvg;
};
__global__ __launch_bounds__(256) void k_proj(ProjArgs p){
  __shared__ __align__(16) u16 As[4096];
  __shared__ __align__(16) u16 Bs[4096];
  int z = blockIdx.z;
  const u16* wT = (z==0) ? p.wT0 : (z==1) ? p.wT1 : (z==2) ? p.wT2 : p.wT3;
  int tid = threadIdx.x;
  Acc acc; acc_zero(acc);
  const u16* A  = p.xh + (size_t)blockIdx.x*128*2048;
  const u16* Bt = wT   + (size_t)blockIdx.y*128*2048;
  gemm_core(A, 2048, Bt, 2048, 2048, As, Bs, acc, tid);
  int w = tid>>6, l = tid&63, q4 = l>>4, m = l&15, wm = w&1, wn = w>>1;
  #pragma unroll
  for (int ti=0; ti<4; ti++)
  #pragma unroll
  for (int tj=0; tj<4; tj++)
  #pragma unroll
  for (int r=0; r<4; r++){
    int trow = blockIdx.x*128 + wm*64 + ti*16 + q4*4 + r;
    int col  = blockIdx.y*128 + wn*64 + tj*16 + m;
    float v = acc.a[ti][tj][r];
    if (z == 3){
      float sg = sigm(v + p.bvg[col]);
      p.vg[(size_t)trow*2048 + col] = f2h(sg);
    } else {
      int b = trow >> 10, i = trow & 1023, h = col >> 7, d = col & 127;
      u16* dst = (z==0) ? p.q : (z==1) ? p.k : p.v;
      dst[(((size_t)(b*16 + h))*1024 + i)*128 + d] = f2h(v);
    }
  }
}

// ---------------- head gate: sigmoid(x @ w_hgate + b), K split over 4 waves ----------------
__global__ __launch_bounds__(256) void k_hgate(const u16* __restrict__ xh, const u16* __restrict__ whgT,
    const float* __restrict__ bhg, float* __restrict__ hg){
  __shared__ float red[4][256];
  int tid = threadIdx.x, w = tid>>6, l = tid&63, q = l>>4, m = l&15;
  int t0 = blockIdx.x*16;
  f32x4 acc = {0.f,0.f,0.f,0.f};
  const u16* xr = xh   + (size_t)(t0 + m)*2048 + w*512;
  const u16* br = whgT + (size_t)m*2048 + w*512;
  #pragma unroll 4
  for (int k = 0; k < 512; k += 32){
    f16x8 a = *(const f16x8*)(xr + k + q*8);
    f16x8 b = *(const f16x8*)(br + k + q*8);
    acc = __builtin_amdgcn_mfma_f32_16x16x32_f16(a, b, acc, 0, 0, 0);
  }
  #pragma unroll
  for (int r = 0; r < 4; r++) red[w][(q*4+r)*16 + m] = acc[r];
  __syncthreads();
  float v = red[0][tid] + red[1][tid] + red[2][tid] + red[3][tid];
  int tl = tid >> 4, h = tid & 15;
  hg[(size_t)(t0 + tl)*16 + h] = sigm(v + bhg[h]);
}

// ---------------- q,k l2norm + rotary (in place) + CoPE logits L ----------------
__global__ __launch_bounds__(256) void k_normrope(u16* __restrict__ qb, u16* __restrict__ kb,
    const float* __restrict__ freqs, const float* __restrict__ cope, float* __restrict__ L){
  __shared__ float ce[2048];
  int tid = threadIdx.x;
  for (int i2 = tid; i2 < 2048; i2 += 256) ce[i2] = cope[i2];
  __syncthreads();
  int w = tid >> 6, l = tid & 63;
  int r = blockIdx.x*4 + w;            // 0..65535
  int isq = (r < 32768) ? 1 : 0;
  int rr = isq ? r : r - 32768;
  int i = rr & 1023;
  u16* base = (isq ? qb : kb) + (size_t)rr*128;
  float v0 = h2f(base[2*l]), v1 = h2f(base[2*l+1]);
  float ss = v0*v0 + v1*v1;
  #pragma unroll
  for (int off = 1; off < 64; off <<= 1) ss += __shfl_xor(ss, off);
  float rn = 1.f / fmaxf(sqrtf(ss), 1e-12f);
  v0 *= rn; v1 *= rn;
  float f = freqs[i*128 + 2*l];
  float sn, cs; sincosf(f, &sn, &cs);
  float o0 = v0*cs - v1*sn, o1 = v1*cs + v0*sn;
  base[2*l] = f2h(o0); base[2*l+1] = f2h(o1);
  if (isq){
    #pragma unroll
    for (int p = 0; p < 16; p++){
      float part = o0*ce[p*128 + 2*l] + o1*ce[p*128 + 2*l + 1];
      #pragma unroll
      for (int off = 1; off < 64; off <<= 1) part += __shfl_xor(part, off);
      if (l == p) L[(size_t)rr*16 + p] = part;
    }
  }
}

// ---------------- sim = 10 * q k^T, causal-packed fp16 (mask = MASKV) ----------------
__global__ __launch_bounds__(256) void k_qk(const u16* __restrict__ qb, const u16* __restrict__ kb,
    u16* __restrict__ S){
  __shared__ __align__(16) u16 As[4096];
  __shared__ __align__(16) u16 Bs[4096];
  int tile = blockIdx.x, bh = blockIdx.y;
  int it = 0;
  #pragma unroll
  for (int t2 = 1; t2 < 8; t2++) if (tile >= (t2*(t2+1))/2) it = t2;
  int jt = tile - (it*(it+1))/2;
  const u16* A  = qb + (size_t)bh*131072 + (size_t)it*16384;
  const u16* Bt = kb + (size_t)bh*131072 + (size_t)jt*16384;
  Acc acc; acc_zero(acc);
  gemm_core(A, 128, Bt, 128, 128, As, Bs, acc, threadIdx.x);
  int tid = threadIdx.x, w = tid>>6, l = tid&63, q = l>>4, m = l&15, wm = w&1, wn = w>>1;
  u16* dst = S + ((size_t)bh*36 + tile)*16384;
  #pragma unroll
  for (int ti=0; ti<4; ti++)
  #pragma unroll
  for (int tj=0; tj<4; tj++)
  #pragma unroll
  for (int r=0; r<4; r++){
    int iloc = wm*64 + ti*16 + q*4 + r;
    int jloc = wn*64 + tj*16 + m;
    float v = acc.a[ti][tj][r] * 10.f;
    if (jt*128 + jloc > it*128 + iloc) v = MASKV;
    dst[(size_t)iloc*128 + jloc] = f2h(v);
  }
}

// ---------------- th_pre mix + CoPE + online softmax stats (in-place S) ----------------
// Lane layout: lane l owns row ii=l>>4 (of 4), j-quad j0=(l&15)*4 within each 64-j tile.
struct CopeArgs { const u16* S; const float* L; const float* thpre; u16* Sout; float* ml; };
__global__ __launch_bounds__(1024) void k_cope(CopeArgs pa){
  __shared__ u16 raw[16*276];       // [g][ii*68 + j], padded strides: conflict-free b64
  __shared__ float thsh[256];       // th_pre[h][g]
  __shared__ float Lsh[1024];       // [h][ii][p]
  int b = blockIdx.y;
  int i0 = (int)(gridDim.x - 1 - blockIdx.x) * 4;   // heavy blocks first
  int tid = threadIdx.x, w = tid>>6, l = tid&63;
  int h = w;                                         // 16 waves = 16 heads
  if (tid < 256) thsh[tid] = pa.thpre[tid];
  Lsh[tid] = pa.L[ ((size_t)((b*16 + (tid>>6))*1024) + i0 + ((tid>>4)&3))*16 + (tid&15) ];
  __syncthreads();
  float th_r[16];
  #pragma unroll
  for (int g = 0; g < 16; g++) th_r[g] = thsh[h*16 + g];
  int ii = l >> 4, j0 = (l & 15)*4;
  int i = i0 + ii, it1 = i >> 7, iloc = i & 127;
  const float* Lrow = Lsh + h*64 + ii*16;
  float carry = 0.f, mrun = -1e30f, lrun = 0.f;
  int tmax = (i0 + 3) >> 6;
  for (int t = tmax; t >= 0; t--){
    int jt1 = (t*64) >> 7, jo = (t*64) & 127;
    __syncthreads();
    {
      int e = tid*4;                 // [0,4096)
      int g = e >> 8, r = e & 255;
      int si = r >> 6, j = r & 63;
      int irow = i0 + si; int it2 = irow >> 7, il2 = irow & 127;
      const u16* src = pa.S + ((size_t)((b*16+g)*36 + (it2*(it2+1))/2 + jt1))*16384
                           + (size_t)il2*128 + jo + j;
      *(u16x4*)(raw + g*276 + si*68 + j) = *(const u16x4*)src;
    }
    __syncthreads();
    float s0=0.f, s1=0.f, s2=0.f, s3=0.f;
    #pragma unroll
    for (int g = 0; g < 16; g++){
      u16x4 v = *(const u16x4*)(raw + g*276 + ii*68 + j0);
      float tg = th_r[g];
      s0 += tg*h2f(v[0]); s1 += tg*h2f(v[1]); s2 += tg*h2f(v[2]); s3 += tg*h2f(v[3]);
    }
    // gates + segmented suffix scan (in-lane 4 + cross-lane 16)
    float g0 = sigm(s0), g1 = sigm(s1), g2 = sigm(s2), g3 = sigm(s3);
    float c3 = g3, c2 = g2 + c3, c1 = g1 + c2, c0 = g0 + c1;
    float T = c0, Tacc = T;
    #pragma unroll
    for (int off = 1; off < 16; off <<= 1){
      float tv = __shfl(Tacc, (l + off) & 63);
      if (((l & 15) + off) < 16) Tacc += tv;
    }
    float Rh = Tacc - T;                         // sum over higher lanes in group
    float rowtot = __shfl(Tacc, l & 48);         // group-first lane = full tile sum
    float sf[4];
    float cc[4] = {c0, c1, c2, c3};
    float ssv[4] = {s0, s1, s2, s3};
    #pragma unroll
    for (int c = 0; c < 4; c++){
      float pos = fminf(cc[c] + Rh + carry, 15.f);
      float pf = floorf(pos);
      float wi = pos - pf;
      int ic = (int)ceilf(pos), ifl = (int)pf;
      float v = ssv[c] + Lrow[ic]*wi + Lrow[ifl]*(1.f - wi);
      sf[c] = v;
    }
    carry += rowtot;
    u16x4 ov;
    #pragma unroll
    for (int c = 0; c < 4; c++){ ov[c] = f2h(sf[c]); sf[c] = h2f(ov[c]); }
    *(u16x4*)(pa.Sout + ((size_t)((b*16+h)*36 + (it1*(it1+1))/2 + jt1))*16384
              + (size_t)iloc*128 + jo + j0) = ov;
    float M = fmaxf(fmaxf(sf[0], sf[1]), fmaxf(sf[2], sf[3]));
    #pragma unroll
    for (int off = 1; off < 16; off <<= 1) M = fmaxf(M, __shfl_xor(M, off));
    float mnew = fmaxf(mrun, M);
    float es = __expf(fminf(sf[0]-mnew,0.f)) + __expf(fminf(sf[1]-mnew,0.f))
             + __expf(fminf(sf[2]-mnew,0.f)) + __expf(fminf(sf[3]-mnew,0.f));
    #pragma unroll
    for (int off = 1; off < 16; off <<= 1) es += __shfl_xor(es, off);
    lrun = lrun*__expf(fminf(mrun - mnew, 0.f)) + es;
    mrun = mnew;
  }
  if ((l & 15) == 0){
    size_t bix = (size_t)(b*16 + h)*1024 + i0 + ii;
    pa.ml[bix] = mrun;
    pa.ml[32768 + bix] = 1.f/fmaxf(lrun, 1e-30f);
  }
}

// ---------------- softmax normalize + th_post mix (packed fp16, in-place S -> attn2) ----------------
struct PostArgs { const u16* S; const float* ml; const float* thpost; u16* Sout; };
__global__ __launch_bounds__(256) void k_postmix(PostArgs pa){
  __shared__ u16 at[16*1040];        // [g][e], stride 1040
  __shared__ _Float16 thsh[256];
  __shared__ float mh[128], rlh[128];
  int tile = blockIdx.x >> 4, sub = blockIdx.x & 15, b = blockIdx.y;
  int it = 0;
  #pragma unroll
  for (int t2=1; t2<8; t2++) if (tile >= (t2*(t2+1))/2) it = t2;
  int tid = threadIdx.x;
  thsh[tid] = (_Float16)pa.thpost[tid];
  if (tid < 128){
    int g = tid >> 3, ii = tid & 7;
    size_t ix = (size_t)(b*16+g)*1024 + it*128 + sub*8 + ii;
    mh[tid] = pa.ml[ix]; rlh[tid] = pa.ml[32768 + ix];
  }
  __syncthreads();
  {
    int g = tid >> 4, l16 = tid & 15;
    const u16* src = pa.S + ((size_t)((b*16+g)*36 + tile))*16384 + sub*1024;
    #pragma unroll
    for (int c = 0; c < 16; c++){
      int e = c*64 + l16*4;
      int ii = e >> 7;
      float mm = mh[g*8+ii], rr = rlh[g*8+ii];
      u16x4 sv = *(const u16x4*)(src + e);
      u16x4 o;
      #pragma unroll
      for (int z2=0; z2<4; z2++) o[z2] = f2h(__expf(fminf(h2f(sv[z2]) - mm, 0.f)) * rr);
      *(u16x4*)(at + g*1040 + e) = o;
    }
  }
  __syncthreads();
  int h = tid >> 4, c16 = tid & 15;
  _Float16 th_h[16];
  #pragma unroll
  for (int g = 0; g < 16; g++) th_h[g] = thsh[h*16 + g];
  u16* dst = pa.Sout + ((size_t)((b*16+h)*36 + tile))*16384 + sub*1024;
  #pragma unroll
  for (int k = 0; k < 16; k++){
    int e = c16*4 + k*64;
    f16x4 a = {0,0,0,0};
    #pragma unroll
    for (int g = 0; g < 16; g++){
      f16x4 v = *(const f16x4*)(at + g*1040 + e);
      a += v * th_h[g];
    }
    *(f16x4*)(dst + e) = a;
  }
}

// ---------------- out = attn2 @ v, fused head/value gates ----------------
struct PvArgs { const u16* S; const u16* vT; const float* hg; const u16* vg; u16* gated; };
__global__ __launch_bounds__(256) void k_pv(PvArgs pa){
  __shared__ __align__(16) u16 As[2048];
  __shared__ __align__(16) u16 Bs[4096];
  int bh = blockIdx.y, b = bh >> 4, h = bh & 15;
  int isub = (int)(gridDim.x - 1 - blockIdx.x);   // heavy blocks first
  int i0 = isub * 64;
  int it1 = i0 >> 7, ibase = i0 & 127;
  int nk = (i0 + 64) / 32;
  const u16* abase = pa.S  + ((size_t)(bh*36 + (it1*(it1+1))/2))*16384;
  const u16* vt    = pa.vT + (size_t)bh*131072;
  int tid = threadIdx.x, w = tid>>6, l = tid&63, q = l>>4, m = l&15, wm = w&1, wn = w>>1;
  f32x4 acc[2][4];
  { f32x4 z = {0.f,0.f,0.f,0.f};
    #pragma unroll
    for (int i2=0;i2<2;i2++)
      #pragma unroll
      for (int j2=0;j2<4;j2++) acc[i2][j2] = z; }
  for (int ks = 0; ks < nk; ks++){
    __syncthreads();
    {
      int row = w*16 + (l>>2);
      async16(abase + (size_t)(ks>>2)*16384 + (size_t)(ibase + row)*128 + (ks&3)*32 + (l&3)*8,
              As + (w*16)*32);
    }
    #pragma unroll
    for (int p2=0; p2<2; p2++){
      int row = w*32 + p2*16 + (l>>2);
      async16(vt + (size_t)row*1024 + ks*32 + (l&3)*8, Bs + (w*32 + p2*16)*32);
    }
    __syncthreads();
    f16x8 af[2], bf[4];
    #pragma unroll
    for (int t=0;t<2;t++) af[t] = *(const f16x8*)(As + (wm*32 + t*16 + m)*32 + q*8);
    #pragma unroll
    for (int t=0;t<4;t++) bf[t] = *(const f16x8*)(Bs + (wn*64 + t*16 + m)*32 + q*8);
    #pragma unroll
    for (int i2=0;i2<2;i2++)
      #pragma unroll
      for (int j2=0;j2<4;j2++)
        acc[i2][j2] = __builtin_amdgcn_mfma_f32_16x16x32_f16(af[i2], bf[j2], acc[i2][j2], 0, 0, 0);
  }
  #pragma unroll
  for (int ti=0; ti<2; ti++)
  #pragma unroll
  for (int tj=0; tj<4; tj++)
  #pragma unroll
  for (int r=0; r<4; r++){
    int i = i0 + wm*32 + ti*16 + q*4 + r;
    int d = wn*64 + tj*16 + m;
    int tok = b*1024 + i;
    float v = acc[ti][tj][r] * pa.hg[(size_t)tok*16 + h] * h2f(pa.vg[(size_t)tok*2048 + h*128 + d]);
    if (v != v) v = 333.f;           // NaN tag: PV-level
    pa.gated[(size_t)tok*2048 + h*128 + d] = f2h(v);
  }
}

// ---------------- final projection -> f32 d_out ----------------
__global__ __launch_bounds__(256) void k_out(const u16* __restrict__ gated, const u16* __restrict__ woT,
    float* __restrict__ out){
  __shared__ __align__(16) u16 As[4096];
  __shared__ __align__(16) u16 Bs[4096];
  Acc acc; acc_zero(acc);
  gemm_core(gated + (size_t)blockIdx.x*128*2048, 2048,
            woT   + (size_t)blockIdx.y*128*2048, 2048, 2048, As, Bs, acc, threadIdx.x);
  int tid = threadIdx.x, w = tid>>6, l = tid&63, q = l>>4, m = l&15, wm = w&1, wn = w>>1;
  #pragma unroll
  for (int ti=0; ti<4; ti++)
  #pragma unroll
  for (int tj=0; tj<4; tj++)
  #pragma unroll
  for (int r=0; r<4; r++){
    int trow = blockIdx.x*128 + wm*64 + ti*16 + q*4 + r;
    int col  = blockIdx.y*128 + wn*64 + tj*16 + m;
    float o = acc.a[ti][tj][r];
    if (o != o) o = 911.f;           // NaN tag: output-GEMM level
    out[(size_t)trow*2048 + col] = o;
  }
}

extern "C" void kernel_launch(void* const* d_in, const int* in_sizes, int n_in,
                              void* d_out, int out_size, void* d_ws, size_t ws_size,
                              hipStream_t stream){
  const float* x      = (const float*)d_in[0];
  const float* freqs  = (const float*)d_in[1];
  const float* w_q    = (const float*)d_in[2];
  const float* w_k    = (const float*)d_in[3];
  const float* w_v    = (const float*)d_in[4];
  const float* cope   = (const float*)d_in[5];
  const float* thpre  = (const float*)d_in[6];
  const float* thpost = (const float*)d_in[7];
  const float* w_vg   = (const float*)d_in[8];
  const float* b_vg   = (const float*)d_in[9];
  const float* w_hg   = (const float*)d_in[10];
  const float* b_hg   = (const float*)d_in[11];
  const float* w_out  = (const float*)d_in[12];

  char* ws = (char*)d_ws;
  size_t off = 0;
  auto alloc = [&](size_t bytes)->char*{ char* r = ws + off; off += (bytes + 255) & ~(size_t)255; return r; };
  u16*   xh    = (u16*)  alloc(8388608);
  u16*   wqT   = (u16*)  alloc(8388608);
  u16*   wkT   = (u16*)  alloc(8388608);
  u16*   wvT   = (u16*)  alloc(8388608);
  u16*   wvgT  = (u16*)  alloc(8388608);
  u16*   woT   = (u16*)  alloc(8388608);
  u16*   whgT  = (u16*)  alloc(65536);
  u16*   qb    = (u16*)  alloc(8388608);
  u16*   kb    = (u16*)  alloc(8388608);
  u16*   vb    = (u16*)  alloc(8388608);
  u16*   vTT   = (u16*)  alloc(8388608);
  u16*   vg    = (u16*)  alloc(8388608);
  u16*   gated = (u16*)  alloc(8388608);
  float* L     = (float*)alloc(2097152);
  float* hg    = (float*)alloc(131072);
  float* ml    = (float*)alloc(262144);
  u16*   S     = (u16*)  alloc(37748736);

  dim3 b256(256);
  PrepArgs pp;
  pp.src[0]=x;    pp.dst[0]=xh;   pp.C[0]=2048;
  pp.src[1]=w_q;  pp.dst[1]=wqT;  pp.C[1]=2048;
  pp.src[2]=w_k;  pp.dst[2]=wkT;  pp.C[2]=2048;
  pp.src[3]=w_v;  pp.dst[3]=wvT;  pp.C[3]=2048;
  pp.src[4]=w_vg; pp.dst[4]=wvgT; pp.C[4]=2048;
  pp.src[5]=w_out;pp.dst[5]=woT;  pp.C[5]=2048;
  pp.src[6]=w_hg; pp.dst[6]=whgT; pp.C[6]=16;
  k_prep<<<dim3(64,64,7), b256, 0, stream>>>(pp);

  ProjArgs pa{ xh, wqT, wkT, wvT, wvgT, qb, kb, vb, vg, b_vg };
  k_proj<<<dim3(16,16,4), b256, 0, stream>>>(pa);
  k_hgate<<<dim3(128), b256, 0, stream>>>(xh, whgT, b_hg, hg);
  k_transpose_h<<<dim3(4,32,32), b256, 0, stream>>>(vb, vTT, 1024, 128, 131072L, 131072L);
  k_normrope<<<dim3(16384), b256, 0, stream>>>(qb, kb, freqs, cope, L);
  k_qk<<<dim3(36,32), b256, 0, stream>>>(qb, kb, S);
  CopeArgs ca{ S, L, thpre, S, ml };
  k_cope<<<dim3(256,2), dim3(1024), 0, stream>>>(ca);
  PostArgs po{ S, ml, thpost, S };
  k_postmix<<<dim3(576,2), b256, 0, stream>>>(po);
  PvArgs pv{ S, vTT, hg, vg, gated };
  k_pv<<<dim3(16,32), b256, 0, stream>>>(pv);
  k_out<<<dim3(16,16), b256, 0, stream>>>(gated, woT, (float*)d_out);
}

// Round 6
// 498.860 us; speedup vs baseline: 1.1566x; 1.0219x over previous
//
#include <hip/hip_runtime.h>
#include <hip/hip_fp16.h>

typedef unsigned short u16;
typedef __attribute__((ext_vector_type(4))) float f32x4;
typedef __attribute__((ext_vector_type(8))) _Float16 f16x8;
typedef __attribute__((ext_vector_type(4))) _Float16 f16x4;
typedef __attribute__((ext_vector_type(8))) unsigned short u16x8;
typedef __attribute__((ext_vector_type(4))) unsigned short u16x4;

#define DEVI __device__ __forceinline__
#define MASKV (-1000.0f)

DEVI u16 f2h(float f){ __half h = __float2half(f); return __half_as_ushort(h); }
DEVI float h2f(u16 v){ return __half2float(__ushort_as_half(v)); }
DEVI float sigm(float s){ float e = __expf(-fabsf(s)); return (s >= 0.f) ? 1.f/(1.f+e) : e/(1.f+e); }

DEVI void async16(const void* g, void* l){
  __builtin_amdgcn_global_load_lds((__attribute__((address_space(1))) const unsigned int*)g,
                                   (__attribute__((address_space(3))) unsigned int*)l, 16, 0, 0);
}

struct Acc { f32x4 a[4][4]; };
DEVI void acc_zero(Acc& a){
  f32x4 z = {0.f,0.f,0.f,0.f};
  #pragma unroll
  for (int i=0;i<4;i++)
    #pragma unroll
    for (int j=0;j<4;j++) a.a[i][j] = z;
}

// C[128 x 128] = A[128 x K] * Bt[128 x K]^T   (fp16, BK=32, m97 structure)
DEVI void gemm_core(const u16* __restrict__ A, int lda, const u16* __restrict__ Bt, int ldb,
                    int K, u16* As, u16* Bs, Acc& acc, int tid)
{
  int w = tid >> 6, l = tid & 63;
  int q = l >> 4, m = l & 15;
  int wm = w & 1, wn = w >> 1;
  for (int k0 = 0; k0 < K; k0 += 32){
    __syncthreads();
    #pragma unroll
    for (int p = 0; p < 2; p++){
      int row = w*32 + p*16 + (l>>2);
      async16(A  + (size_t)row*lda + k0 + (l&3)*8, As + (w*32 + p*16)*32);
      async16(Bt + (size_t)row*ldb + k0 + (l&3)*8, Bs + (w*32 + p*16)*32);
    }
    __syncthreads();
    f16x8 af[4], bf[4];
    #pragma unroll
    for (int t = 0; t < 4; t++){
      af[t] = *(const f16x8*)(As + (wm*64 + t*16 + m)*32 + q*8);
      bf[t] = *(const f16x8*)(Bs + (wn*64 + t*16 + m)*32 + q*8);
    }
    #pragma unroll
    for (int i = 0; i < 4; i++)
      #pragma unroll
      for (int j = 0; j < 4; j++)
        acc.a[i][j] = __builtin_amdgcn_mfma_f32_16x16x32_f16(af[i], bf[j], acc.a[i][j], 0, 0, 0);
  }
}

// ---------------- fused prep: x convert (z=0) + 6 weight transposes (z=1..6) ----------------
struct PrepArgs {
  const float* src[7];
  u16* dst[7];
  int C[7];
};
__global__ __launch_bounds__(256) void k_prep(PrepArgs p){
  __shared__ u16 t[32][33];
  int z = blockIdx.z;
  if (z == 0){
    int i = ((blockIdx.y*64 + blockIdx.x)*256 + threadIdx.x)*4;
    f32x4 v = *(const f32x4*)(p.src[0] + i);
    u16x4 o;
    #pragma unroll
    for (int z2=0; z2<4; z2++) o[z2] = f2h(v[z2]);
    *(u16x4*)(p.dst[0] + i) = o;
    return;
  }
  const float* src = p.src[z]; u16* dst = p.dst[z];
  int R = 2048, C = p.C[z];
  int c0 = blockIdx.x*32, r0 = blockIdx.y*32;
  if (c0 >= C) return;
  int tx = threadIdx.x & 31, ty = threadIdx.x >> 5;
  #pragma unroll
  for (int i = ty; i < 32; i += 8){
    int r = r0 + i, c = c0 + tx;
    if (r < R && c < C) t[i][tx] = f2h(src[(size_t)r*C + c]);
  }
  __syncthreads();
  #pragma unroll
  for (int i = ty; i < 32; i += 8){
    int rr = c0 + i, cc = r0 + tx;
    if (rr < C && cc < R) dst[(size_t)rr*R + cc] = t[tx][i];
  }
}

// ---------------- transpose u16 [R][C] -> [C][R], batched ----------------
__global__ __launch_bounds__(256) void k_transpose_h(const u16* __restrict__ src, u16* __restrict__ dst,
    int R, int C, long sps, long dps){
  __shared__ u16 t[32][33];
  src += (size_t)blockIdx.z * sps; dst += (size_t)blockIdx.z * dps;
  int c0 = blockIdx.x*32, r0 = blockIdx.y*32;
  int tx = threadIdx.x & 31, ty = threadIdx.x >> 5;
  #pragma unroll
  for (int i = ty; i < 32; i += 8){
    int r = r0 + i, c = c0 + tx;
    if (r < R && c < C) t[i][tx] = src[(size_t)r*C + c];
  }
  __syncthreads();
  #pragma unroll
  for (int i = ty; i < 32; i += 8){
    int rr = c0 + i, cc = r0 + tx;
    if (rr < C && cc < R) dst[(size_t)rr*R + cc] = t[tx][i];
  }
}

// ---------------- QKV + vgate projections ----------------
struct ProjArgs {
  const u16* xh;
  const u16* wT0; const u16* wT1; const u16* wT2; const u16* wT3;
  u16* q; u16* k; u16* v; u16* vg;
  const float* bvg;
};
__global__ __launch_bounds__(256) void k_proj(ProjArgs p){
  __shared__ __align__(16) u16 As[4096];
  __shared__ __align__(16) u16 Bs[4096];
  int z = blockIdx.z;
  const u16* wT = (z==0) ? p.wT0 : (z==1) ? p.wT1 : (z==2) ? p.wT2 : p.wT3;
  int tid = threadIdx.x;
  Acc acc; acc_zero(acc);
  const u16* A  = p.xh + (size_t)blockIdx.x*128*2048;
  const u16* Bt = wT   + (size_t)blockIdx.y*128*2048;
  gemm_core(A, 2048, Bt, 2048, 2048, As, Bs, acc, tid);
  int w = tid>>6, l = tid&63, q4 = l>>4, m = l&15, wm = w&1, wn = w>>1;
  #pragma unroll
  for (int ti=0; ti<4; ti++)
  #pragma unroll
  for (int tj=0; tj<4; tj++)
  #pragma unroll
  for (int r=0; r<4; r++){
    int trow = blockIdx.x*128 + wm*64 + ti*16 + q4*4 + r;
    int col  = blockIdx.y*128 + wn*64 + tj*16 + m;
    float v = acc.a[ti][tj][r];
    if (z == 3){
      float sg = sigm(v + p.bvg[col]);
      p.vg[(size_t)trow*2048 + col] = f2h(sg);
    } else {
      int b = trow >> 10, i = trow & 1023, h = col >> 7, d = col & 127;
      u16* dst = (z==0) ? p.q : (z==1) ? p.k : p.v;
      dst[(((size_t)(b*16 + h))*1024 + i)*128 + d] = f2h(v);
    }
  }
}

// ---------------- head gate: sigmoid(x @ w_hgate + b), K split over 4 waves ----------------
__global__ __launch_bounds__(256) void k_hgate(const u16* __restrict__ xh, const u16* __restrict__ whgT,
    const float* __restrict__ bhg, float* __restrict__ hg){
  __shared__ float red[4][256];
  int tid = threadIdx.x, w = tid>>6, l = tid&63, q = l>>4, m = l&15;
  int t0 = blockIdx.x*16;
  f32x4 acc = {0.f,0.f,0.f,0.f};
  const u16* xr = xh   + (size_t)(t0 + m)*2048 + w*512;
  const u16* br = whgT + (size_t)m*2048 + w*512;
  #pragma unroll 4
  for (int k = 0; k < 512; k += 32){
    f16x8 a = *(const f16x8*)(xr + k + q*8);
    f16x8 b = *(const f16x8*)(br + k + q*8);
    acc = __builtin_amdgcn_mfma_f32_16x16x32_f16(a, b, acc, 0, 0, 0);
  }
  #pragma unroll
  for (int r = 0; r < 4; r++) red[w][(q*4+r)*16 + m] = acc[r];
  __syncthreads();
  float v = red[0][tid] + red[1][tid] + red[2][tid] + red[3][tid];
  int tl = tid >> 4, h = tid & 15;
  hg[(size_t)(t0 + tl)*16 + h] = sigm(v + bhg[h]);
}

// ---------------- q,k l2norm + rotary (in place) + CoPE logits L ----------------
__global__ __launch_bounds__(256) void k_normrope(u16* __restrict__ qb, u16* __restrict__ kb,
    const float* __restrict__ freqs, const float* __restrict__ cope, float* __restrict__ L){
  __shared__ float ce[2048];
  int tid = threadIdx.x;
  for (int i2 = tid; i2 < 2048; i2 += 256) ce[i2] = cope[i2];
  __syncthreads();
  int w = tid >> 6, l = tid & 63;
  int r = blockIdx.x*4 + w;            // 0..65535
  int isq = (r < 32768) ? 1 : 0;
  int rr = isq ? r : r - 32768;
  int i = rr & 1023;
  u16* base = (isq ? qb : kb) + (size_t)rr*128;
  float v0 = h2f(base[2*l]), v1 = h2f(base[2*l+1]);
  float ss = v0*v0 + v1*v1;
  #pragma unroll
  for (int off = 1; off < 64; off <<= 1) ss += __shfl_xor(ss, off);
  float rn = 1.f / fmaxf(sqrtf(ss), 1e-12f);
  v0 *= rn; v1 *= rn;
  float f = freqs[i*128 + 2*l];
  float sn, cs; sincosf(f, &sn, &cs);
  float o0 = v0*cs - v1*sn, o1 = v1*cs + v0*sn;
  base[2*l] = f2h(o0); base[2*l+1] = f2h(o1);
  if (isq){
    #pragma unroll
    for (int p = 0; p < 16; p++){
      float part = o0*ce[p*128 + 2*l] + o1*ce[p*128 + 2*l + 1];
      #pragma unroll
      for (int off = 1; off < 64; off <<= 1) part += __shfl_xor(part, off);
      if (l == p) L[(size_t)rr*16 + p] = part;
    }
  }
}

// ---------------- sim = 10*q k^T: A-resident 64-row tile, loop j-tiles ----------------
__global__ __launch_bounds__(256) void k_qk(const u16* __restrict__ qb, const u16* __restrict__ kb,
    u16* __restrict__ S){
  __shared__ __align__(16) u16 As[8192];    // 4 chunks x 64 rows x 32
  __shared__ __align__(16) u16 Bs[16384];   // 4 chunks x 128 rows x 32
  int bh = blockIdx.y;
  int bx = 15 - (int)blockIdx.x;            // heavy blocks first
  int i0 = bx*64, it = bx >> 1;
  int njt = (bx + 2) >> 1;
  int tid = threadIdx.x, w = tid>>6, l = tid&63, q = l>>4, m = l&15, wm = w&1, wn = w>>1;
  const u16* qbase = qb + (size_t)bh*131072;
  const u16* kbase = kb + (size_t)bh*131072;
  // stage A once (resident)
  #pragma unroll
  for (int sub = 0; sub < 4; sub++){
    int row = w*16 + (l>>2);
    async16(qbase + (size_t)(i0 + row)*128 + sub*32 + (l&3)*8, As + sub*2048 + (w*16)*32);
  }
  u16* dstbase = S + ((size_t)bh*36 + (it*(it+1))/2)*16384 + (size_t)((bx&1)*64)*128;
  for (int jt = 0; jt < njt; jt++){
    __syncthreads();
    #pragma unroll
    for (int sub = 0; sub < 4; sub++)
      #pragma unroll
      for (int p = 0; p < 2; p++){
        int row = w*32 + p*16 + (l>>2);
        async16(kbase + (size_t)(jt*128 + row)*128 + sub*32 + (l&3)*8,
                Bs + sub*4096 + (w*32 + p*16)*32);
      }
    __syncthreads();
    f32x4 acc[2][4];
    { f32x4 z = {0.f,0.f,0.f,0.f};
      #pragma unroll
      for (int a2=0;a2<2;a2++)
        #pragma unroll
        for (int b2=0;b2<4;b2++) acc[a2][b2] = z; }
    #pragma unroll
    for (int kc = 0; kc < 4; kc++){
      f16x8 af[2], bf[4];
      #pragma unroll
      for (int t = 0; t < 2; t++) af[t] = *(const f16x8*)(As + kc*2048 + (wm*32 + t*16 + m)*32 + q*8);
      #pragma unroll
      for (int t = 0; t < 4; t++) bf[t] = *(const f16x8*)(Bs + kc*4096 + (wn*64 + t*16 + m)*32 + q*8);
      #pragma unroll
      for (int a2 = 0; a2 < 2; a2++)
        #pragma unroll
        for (int b2 = 0; b2 < 4; b2++)
          acc[a2][b2] = __builtin_amdgcn_mfma_f32_16x16x32_f16(af[a2], bf[b2], acc[a2][b2], 0, 0, 0);
    }
    u16* dst = dstbase + (size_t)jt*16384;
    #pragma unroll
    for (int ti=0; ti<2; ti++)
    #pragma unroll
    for (int tj=0; tj<4; tj++)
    #pragma unroll
    for (int r=0; r<4; r++){
      int iloc = wm*32 + ti*16 + q*4 + r;
      int jloc = wn*64 + tj*16 + m;
      float v = acc[ti][tj][r] * 10.f;
      if (jt*128 + jloc > i0 + iloc) v = MASKV;
      dst[(size_t)iloc*128 + jloc] = f2h(v);
    }
  }
}

// ---------------- th_pre mix + CoPE + online softmax stats (in-place S) ----------------
struct CopeArgs { const u16* S; const float* L; const float* thpre; u16* Sout; float* ml; };
__global__ __launch_bounds__(1024) void k_cope(CopeArgs pa){
  __shared__ u16 raw[16*276];       // [g][ii*68 + j], padded strides: conflict-free b64
  __shared__ float thsh[256];       // th_pre[h][g]
  __shared__ float Lsh[1024];       // [h][ii][p]
  int b = blockIdx.y;
  int i0 = (int)(gridDim.x - 1 - blockIdx.x) * 4;   // heavy blocks first
  int tid = threadIdx.x, w = tid>>6, l = tid&63;
  int h = w;                                         // 16 waves = 16 heads
  if (tid < 256) thsh[tid] = pa.thpre[tid];
  Lsh[tid] = pa.L[ ((size_t)((b*16 + (tid>>6))*1024) + i0 + ((tid>>4)&3))*16 + (tid&15) ];
  __syncthreads();
  float th_r[16];
  #pragma unroll
  for (int g = 0; g < 16; g++) th_r[g] = thsh[h*16 + g];
  int ii = l >> 4, j0 = (l & 15)*4;
  int i = i0 + ii, it1 = i >> 7, iloc = i & 127;
  const float* Lrow = Lsh + h*64 + ii*16;
  float carry = 0.f, mrun = -1e30f, lrun = 0.f;
  int tmax = (i0 + 3) >> 6;
  for (int t = tmax; t >= 0; t--){
    int jt1 = (t*64) >> 7, jo = (t*64) & 127;
    __syncthreads();
    {
      int e = tid*4;                 // [0,4096)
      int g = e >> 8, r = e & 255;
      int si = r >> 6, j = r & 63;
      int irow = i0 + si; int it2 = irow >> 7, il2 = irow & 127;
      const u16* src = pa.S + ((size_t)((b*16+g)*36 + (it2*(it2+1))/2 + jt1))*16384
                           + (size_t)il2*128 + jo + j;
      *(u16x4*)(raw + g*276 + si*68 + j) = *(const u16x4*)src;
    }
    __syncthreads();
    float s0=0.f, s1=0.f, s2=0.f, s3=0.f;
    #pragma unroll
    for (int g = 0; g < 16; g++){
      u16x4 v = *(const u16x4*)(raw + g*276 + ii*68 + j0);
      float tg = th_r[g];
      s0 += tg*h2f(v[0]); s1 += tg*h2f(v[1]); s2 += tg*h2f(v[2]); s3 += tg*h2f(v[3]);
    }
    // gates + segmented suffix scan (in-lane 4 + cross-lane 16)
    float g0 = sigm(s0), g1 = sigm(s1), g2 = sigm(s2), g3 = sigm(s3);
    float c3 = g3, c2 = g2 + c3, c1 = g1 + c2, c0 = g0 + c1;
    float T = c0, Tacc = T;
    #pragma unroll
    for (int off = 1; off < 16; off <<= 1){
      float tv = __shfl(Tacc, (l + off) & 63);
      if (((l & 15) + off) < 16) Tacc += tv;
    }
    float Rh = Tacc - T;                         // sum over higher lanes in group
    float rowtot = __shfl(Tacc, l & 48);         // group-first lane = full tile sum
    float sf[4];
    float cc[4] = {c0, c1, c2, c3};
    float ssv[4] = {s0, s1, s2, s3};
    #pragma unroll
    for (int c = 0; c < 4; c++){
      float pos = fminf(cc[c] + Rh + carry, 15.f);
      float pf = floorf(pos);
      float wi = pos - pf;
      int ic = (int)ceilf(pos), ifl = (int)pf;
      float v = ssv[c] + Lrow[ic]*wi + Lrow[ifl]*(1.f - wi);
      sf[c] = v;
    }
    carry += rowtot;
    u16x4 ov;
    #pragma unroll
    for (int c = 0; c < 4; c++){ ov[c] = f2h(sf[c]); sf[c] = h2f(ov[c]); }
    *(u16x4*)(pa.Sout + ((size_t)((b*16+h)*36 + (it1*(it1+1))/2 + jt1))*16384
              + (size_t)iloc*128 + jo + j0) = ov;
    float M = fmaxf(fmaxf(sf[0], sf[1]), fmaxf(sf[2], sf[3]));
    #pragma unroll
    for (int off = 1; off < 16; off <<= 1) M = fmaxf(M, __shfl_xor(M, off));
    float mnew = fmaxf(mrun, M);
    float es = __expf(fminf(sf[0]-mnew,0.f)) + __expf(fminf(sf[1]-mnew,0.f))
             + __expf(fminf(sf[2]-mnew,0.f)) + __expf(fminf(sf[3]-mnew,0.f));
    #pragma unroll
    for (int off = 1; off < 16; off <<= 1) es += __shfl_xor(es, off);
    lrun = lrun*__expf(fminf(mrun - mnew, 0.f)) + es;
    mrun = mnew;
  }
  if ((l & 15) == 0){
    size_t bix = (size_t)(b*16 + h)*1024 + i0 + ii;
    pa.ml[bix] = mrun;
    pa.ml[32768 + bix] = 1.f/fmaxf(lrun, 1e-30f);
  }
}

// ---------------- softmax normalize + th_post mix (packed fp16, in-place S -> attn2) ----------------
struct PostArgs { const u16* S; const float* ml; const float* thpost; u16* Sout; };
__global__ __launch_bounds__(256) void k_postmix(PostArgs pa){
  __shared__ u16 at[16*1040];        // [g][e], stride 1040
  __shared__ _Float16 thsh[256];
  __shared__ float mh[128], rlh[128];
  int tile = blockIdx.x >> 4, sub = blockIdx.x & 15, b = blockIdx.y;
  int it = 0;
  #pragma unroll
  for (int t2=1; t2<8; t2++) if (tile >= (t2*(t2+1))/2) it = t2;
  int tid = threadIdx.x;
  thsh[tid] = (_Float16)pa.thpost[tid];
  if (tid < 128){
    int g = tid >> 3, ii = tid & 7;
    size_t ix = (size_t)(b*16+g)*1024 + it*128 + sub*8 + ii;
    mh[tid] = pa.ml[ix]; rlh[tid] = pa.ml[32768 + ix];
  }
  __syncthreads();
  {
    int g = tid >> 4, l16 = tid & 15;
    const u16* src = pa.S + ((size_t)((b*16+g)*36 + tile))*16384 + sub*1024;
    #pragma unroll
    for (int c = 0; c < 16; c++){
      int e = c*64 + l16*4;
      int ii = e >> 7;
      float mm = mh[g*8+ii], rr = rlh[g*8+ii];
      u16x4 sv = *(const u16x4*)(src + e);
      u16x4 o;
      #pragma unroll
      for (int z2=0; z2<4; z2++) o[z2] = f2h(__expf(fminf(h2f(sv[z2]) - mm, 0.f)) * rr);
      *(u16x4*)(at + g*1040 + e) = o;
    }
  }
  __syncthreads();
  int h = tid >> 4, c16 = tid & 15;
  _Float16 th_h[16];
  #pragma unroll
  for (int g = 0; g < 16; g++) th_h[g] = thsh[h*16 + g];
  u16* dst = pa.Sout + ((size_t)((b*16+h)*36 + tile))*16384 + sub*1024;
  #pragma unroll
  for (int k = 0; k < 16; k++){
    int e = c16*4 + k*64;
    f16x4 a = {0,0,0,0};
    #pragma unroll
    for (int g = 0; g < 16; g++){
      f16x4 v = *(const f16x4*)(at + g*1040 + e);
      a += v * th_h[g];
    }
    *(f16x4*)(dst + e) = a;
  }
}

// ---------------- out = attn2 @ v, fused head/value gates, BK=128 chunks ----------------
struct PvArgs { const u16* S; const u16* vT; const float* hg; const u16* vg; u16* gated; };
__global__ __launch_bounds__(256) void k_pv(PvArgs pa){
  __shared__ __align__(16) u16 As[8192];    // 4 sub x 64 rows x 32
  __shared__ __align__(16) u16 Bs[16384];   // 4 sub x 128 rows x 32
  int bh = blockIdx.y, b = bh >> 4, h = bh & 15;
  int bx = 15 - (int)blockIdx.x;            // heavy blocks first
  int i0 = bx*64, it = bx >> 1;
  int nc = (bx + 2) >> 1;
  int tid = threadIdx.x, w = tid>>6, l = tid&63, q = l>>4, m = l&15, wm = w&1, wn = w>>1;
  const u16* abase = pa.S + ((size_t)bh*36 + (it*(it+1))/2)*16384 + (size_t)((bx&1)*64)*128;
  const u16* vt    = pa.vT + (size_t)bh*131072;
  f32x4 acc[2][4];
  { f32x4 z = {0.f,0.f,0.f,0.f};
    #pragma unroll
    for (int a2=0;a2<2;a2++)
      #pragma unroll
      for (int b2=0;b2<4;b2++) acc[a2][b2] = z; }
  for (int jc = 0; jc < nc; jc++){
    __syncthreads();
    #pragma unroll
    for (int sub = 0; sub < 4; sub++){
      int row = w*16 + (l>>2);
      async16(abase + (size_t)jc*16384 + (size_t)row*128 + sub*32 + (l&3)*8,
              As + sub*2048 + (w*16)*32);
      #pragma unroll
      for (int p = 0; p < 2; p++){
        int brow = w*32 + p*16 + (l>>2);
        async16(vt + (size_t)brow*1024 + jc*128 + sub*32 + (l&3)*8,
                Bs + sub*4096 + (w*32 + p*16)*32);
      }
    }
    __syncthreads();
    #pragma unroll
    for (int kc = 0; kc < 4; kc++){
      f16x8 af[2], bf[4];
      #pragma unroll
      for (int t = 0; t < 2; t++) af[t] = *(const f16x8*)(As + kc*2048 + (wm*32 + t*16 + m)*32 + q*8);
      #pragma unroll
      for (int t = 0; t < 4; t++) bf[t] = *(const f16x8*)(Bs + kc*4096 + (wn*64 + t*16 + m)*32 + q*8);
      #pragma unroll
      for (int a2 = 0; a2 < 2; a2++)
        #pragma unroll
        for (int b2 = 0; b2 < 4; b2++)
          acc[a2][b2] = __builtin_amdgcn_mfma_f32_16x16x32_f16(af[a2], bf[b2], acc[a2][b2], 0, 0, 0);
    }
  }
  #pragma unroll
  for (int ti=0; ti<2; ti++)
  #pragma unroll
  for (int tj=0; tj<4; tj++)
  #pragma unroll
  for (int r=0; r<4; r++){
    int i = i0 + wm*32 + ti*16 + q*4 + r;
    int d = wn*64 + tj*16 + m;
    int tok = b*1024 + i;
    float v = acc[ti][tj][r] * pa.hg[(size_t)tok*16 + h] * h2f(pa.vg[(size_t)tok*2048 + h*128 + d]);
    if (v != v) v = 333.f;           // NaN tag: PV-level
    pa.gated[(size_t)tok*2048 + h*128 + d] = f2h(v);
  }
}

// ---------------- final projection -> f32 d_out (M=64 tiles, 512 blocks) ----------------
__global__ __launch_bounds__(256) void k_out(const u16* __restrict__ gated, const u16* __restrict__ woT,
    float* __restrict__ out){
  __shared__ __align__(16) u16 As[2048];
  __shared__ __align__(16) u16 Bs[4096];
  int bx = blockIdx.x;                // col tile (16)
  int by = blockIdx.y;                // row tile (32)
  int trow0 = by*64, c0 = bx*128;
  int tid = threadIdx.x, w = tid>>6, l = tid&63, q = l>>4, m = l&15, wm = w&1, wn = w>>1;
  f32x4 acc[2][4];
  { f32x4 z = {0.f,0.f,0.f,0.f};
    #pragma unroll
    for (int a2=0;a2<2;a2++)
      #pragma unroll
      for (int b2=0;b2<4;b2++) acc[a2][b2] = z; }
  for (int k0 = 0; k0 < 2048; k0 += 32){
    __syncthreads();
    {
      int row = w*16 + (l>>2);
      async16(gated + (size_t)(trow0 + row)*2048 + k0 + (l&3)*8, As + (w*16)*32);
    }
    #pragma unroll
    for (int p = 0; p < 2; p++){
      int row = w*32 + p*16 + (l>>2);
      async16(woT + (size_t)(c0 + row)*2048 + k0 + (l&3)*8, Bs + (w*32 + p*16)*32);
    }
    __syncthreads();
    f16x8 af[2], bf[4];
    #pragma unroll
    for (int t = 0; t < 2; t++) af[t] = *(const f16x8*)(As + (wm*32 + t*16 + m)*32 + q*8);
    #pragma unroll
    for (int t = 0; t < 4; t++) bf[t] = *(const f16x8*)(Bs + (wn*64 + t*16 + m)*32 + q*8);
    #pragma unroll
    for (int a2 = 0; a2 < 2; a2++)
      #pragma unroll
      for (int b2 = 0; b2 < 4; b2++)
        acc[a2][b2] = __builtin_amdgcn_mfma_f32_16x16x32_f16(af[a2], bf[b2], acc[a2][b2], 0, 0, 0);
  }
  #pragma unroll
  for (int ti=0; ti<2; ti++)
  #pragma unroll
  for (int tj=0; tj<4; tj++)
  #pragma unroll
  for (int r=0; r<4; r++){
    int trow = trow0 + wm*32 + ti*16 + q*4 + r;
    int col  = c0 + wn*64 + tj*16 + m;
    float o = acc[ti][tj][r];
    if (o != o) o = 911.f;           // NaN tag: output-GEMM level
    out[(size_t)trow*2048 + col] = o;
  }
}

extern "C" void kernel_launch(void* const* d_in, const int* in_sizes, int n_in,
                              void* d_out, int out_size, void* d_ws, size_t ws_size,
                              hipStream_t stream){
  const float* x      = (const float*)d_in[0];
  const float* freqs  = (const float*)d_in[1];
  const float* w_q    = (const float*)d_in[2];
  const float* w_k    = (const float*)d_in[3];
  const float* w_v    = (const float*)d_in[4];
  const float* cope   = (const float*)d_in[5];
  const float* thpre  = (const float*)d_in[6];
  const float* thpost = (const float*)d_in[7];
  const float* w_vg   = (const float*)d_in[8];
  const float* b_vg   = (const float*)d_in[9];
  const float* w_hg   = (const float*)d_in[10];
  const float* b_hg   = (const float*)d_in[11];
  const float* w_out  = (const float*)d_in[12];

  char* ws = (char*)d_ws;
  size_t off = 0;
  auto alloc = [&](size_t bytes)->char*{ char* r = ws + off; off += (bytes + 255) & ~(size_t)255; return r; };
  u16*   xh    = (u16*)  alloc(8388608);
  u16*   wqT   = (u16*)  alloc(8388608);
  u16*   wkT   = (u16*)  alloc(8388608);
  u16*   wvT   = (u16*)  alloc(8388608);
  u16*   wvgT  = (u16*)  alloc(8388608);
  u16*   woT   = (u16*)  alloc(8388608);
  u16*   whgT  = (u16*)  alloc(65536);
  u16*   qb    = (u16*)  alloc(8388608);
  u16*   kb    = (u16*)  alloc(8388608);
  u16*   vb    = (u16*)  alloc(8388608);
  u16*   vTT   = (u16*)  alloc(8388608);
  u16*   vg    = (u16*)  alloc(8388608);
  u16*   gated = (u16*)  alloc(8388608);
  float* L     = (float*)alloc(2097152);
  float* hg    = (float*)alloc(131072);
  float* ml    = (float*)alloc(262144);
  u16*   S     = (u16*)  alloc(37748736);

  dim3 b256(256);
  PrepArgs pp;
  pp.src[0]=x;    pp.dst[0]=xh;   pp.C[0]=2048;
  pp.src[1]=w_q;  pp.dst[1]=wqT;  pp.C[1]=2048;
  pp.src[2]=w_k;  pp.dst[2]=wkT;  pp.C[2]=2048;
  pp.src[3]=w_v;  pp.dst[3]=wvT;  pp.C[3]=2048;
  pp.src[4]=w_vg; pp.dst[4]=wvgT; pp.C[4]=2048;
  pp.src[5]=w_out;pp.dst[5]=woT;  pp.C[5]=2048;
  pp.src[6]=w_hg; pp.dst[6]=whgT; pp.C[6]=16;
  k_prep<<<dim3(64,64,7), b256, 0, stream>>>(pp);

  ProjArgs pa{ xh, wqT, wkT, wvT, wvgT, qb, kb, vb, vg, b_vg };
  k_proj<<<dim3(16,16,4), b256, 0, stream>>>(pa);
  k_hgate<<<dim3(128), b256, 0, stream>>>(xh, whgT, b_hg, hg);
  k_transpose_h<<<dim3(4,32,32), b256, 0, stream>>>(vb, vTT, 1024, 128, 131072L, 131072L);
  k_normrope<<<dim3(16384), b256, 0, stream>>>(qb, kb, freqs, cope, L);
  k_qk<<<dim3(16,32), b256, 0, stream>>>(qb, kb, S);
  CopeArgs ca{ S, L, thpre, S, ml };
  k_cope<<<dim3(256,2), dim3(1024), 0, stream>>>(ca);
  PostArgs po{ S, ml, thpost, S };
  k_postmix<<<dim3(576,2), b256, 0, stream>>>(po);
  PvArgs pv{ S, vTT, hg, vg, gated };
  k_pv<<<dim3(16,32), b256, 0, stream>>>(pv);
  k_out<<<dim3(16,32), b256, 0, stream>>>(gated, woT, (float*)d_out);
}